// Round 8
// baseline (165.088 us; speedup 1.0000x reference)
//
#include <hip/hip_runtime.h>
#include <math.h>

#define NROWS 1000
#define TWO_R_N 2160.0f   // 2*RADIUS*NUM_POINTS
typedef unsigned int uint;
typedef unsigned long long ull;

__device__ __forceinline__ float wsumf(float v){
#pragma unroll
  for(int o=32;o;o>>=1) v += __shfl_xor(v,o,64);
  return v;
}
__device__ __forceinline__ float wmaxf(float v){
#pragma unroll
  for(int o=32;o;o>>=1) v = fmaxf(v,__shfl_xor(v,o,64));
  return v;
}

// 1024 blocks = 64 batches x 16 priors; 4 blocks/CU share batch b = x&63 via L2.
// Pass 1: coalesced float4 staging -> DENSE LDS (b128 writes, 0 conflicts)
//         -> quad-per-row b32-grid reads (2-way banks = free).
__global__ __launch_bounds__(256,4) void clr_task(const float* __restrict__ feat,
                                                  const float* __restrict__ lab,
                                                  float* __restrict__ ws)
{
  const int b = blockIdx.x & 63;
  const int l = blockIdx.x >> 6;
  const float* __restrict__ F = feat + (size_t)b*NROWS*78;
  const float* __restrict__ P = lab + ((size_t)b*16 + l)*78;

  __shared__ __align__(16) float sBuf[4992];      // one 64-row chunk, dense (19968 B)
  __shared__ __align__(16) float4 sRow[NROWS];    // (S, r*t, c0, c1)  16000 B
  __shared__ float red[16];
  __shared__ int selIdx[64];

  const int tid=threadIdx.x, wave=tid>>6, lane=tid&63;
  const int rloc = tid>>2, q = tid&3;             // quad-per-row within chunk

  // prior: 18 interleaved point-columns for this q (uniform per quad-slot, L1-cached)
  float pv[18];
#pragma unroll
  for(int s=0;s<18;++s) pv[s] = P[6+q+4*s];
  const float2* Pf2 = (const float2*)P;
  const float2 p01=Pf2[0], p23=Pf2[1], p45=Pf2[2];

  float accR=0.f, accT=0.f, accD=0.f, accL=0.f;

  // prefetch chunk 0 (rows 0..63), fully coalesced float4
  float4 pre[5];
  {
    const float4* src=(const float4*)F;
#pragma unroll
    for(int j2=0;j2<5;++j2){ int idx=tid+256*j2; if(idx<1248) pre[j2]=src[idx]; }
  }

  for(int c=0;c<16;++c){
    const int nf4 = (c<15)?1248:780;              // chunk 15 has 40 rows
    // dense b128 stores: consecutive addresses -> zero bank conflicts
    {
      float4* d4=(float4*)sBuf;
#pragma unroll
      for(int j2=0;j2<5;++j2){ int idx=tid+256*j2; if(idx<nf4) d4[idx]=pre[j2]; }
    }
    __syncthreads();                              // chunk visible
    // issue next chunk's global loads (fly during compute)
    if(c<15){
      const int nn = (c+1<15)?1248:780;
      const float4* src=(const float4*)(F + (size_t)(c+1)*4992);
#pragma unroll
      for(int j2=0;j2<5;++j2){ int idx=tid+256*j2; if(idx<nn) pre[j2]=src[idx]; }
    }
    // compute chunk c: thread q reads cols {6+q+4s}; (s,s+9) fuse to ds_read2_b32
    const int rows = (c<15)?64:40;
    if(rloc<rows){
      const float* rp = sBuf + rloc*78;
      float part=0.f;
#pragma unroll
      for(int s=0;s<9;++s){
        part += fabsf(rp[6+q+4*s]      - pv[s]);
        part += fabsf(rp[6+q+4*(s+9)]  - pv[s+9]);
      }
      float s1 = part + __shfl_xor(part,1,64);
      float S  = s1   + __shfl_xor(s1,  2,64);
      if(q==0){
        int r = c*64 + rloc;
        const float2* rp2=(const float2*)rp;
        float2 c01=rp2[0], c23=rp2[1], c45=rp2[2];
        float dr3=c23.y-p23.y, dr4=c45.x-p45.x;
        float r2=dr3*dr3+dr4*dr4;
        float tt=c45.y-p45.y;
        sRow[r]=make_float4(S, sqrtf(r2)*tt, c01.x, c01.y);
        accR+=r2; accT+=tt*tt;
        float dd=S*(1.f/72.f); accD+=dd*dd;
        accL += 1.f-(TWO_R_N-S)/(TWO_R_N+S+1e-9f);
      }
    }
    __syncthreads();                              // reads done before next rewrite
  }

  {
    float vR=wsumf(accR), vT=wsumf(accT), vD=wsumf(accD), vL=wsumf(accL);
    if(lane==0){ red[wave*4]=vR; red[wave*4+1]=vT; red[wave*4+2]=vD; red[wave*4+3]=vL; }
  }
  __syncthreads();
  if (wave != 0) return;                          // waves 1-3 free their SIMD slots

  // ---- wave-0 tail: normalizers ----
  float R=0.f,T=0.f,D=0.f,L=0.f;
#pragma unroll
  for(int w=0;w<4;w++){ R+=red[w*4]; T+=red[w*4+1]; D+=red[w*4+2]; L+=red[w*4+3]; }
  float Nr=fmaxf(sqrtf(R),1e-12f), Nt=fmaxf(sqrtf(T),1e-12f), Nd=fmaxf(sqrtf(D),1e-12f);
  const float inv = 1.f/(Nr*Nt*Nd);
  int k=(int)L; if(k<1)k=1; if(k>64)k=64;         // trunc == astype(int32)

  // ---- column log-softmax over 1000 rows ----
  float m0=-INFINITY, m1=-INFINITY;
#pragma unroll
  for(int t=0;t<16;++t){ int i=t*64+lane; if(i<NROWS){ float4 v=sRow[i]; m0=fmaxf(m0,v.z); m1=fmaxf(m1,v.w);} }
  m0=wmaxf(m0); m1=wmaxf(m1);
  float s0=0.f, s1=0.f;
#pragma unroll
  for(int t=0;t<16;++t){ int i=t*64+lane; if(i<NROWS){ float4 v=sRow[i]; s0+=__expf(v.z-m0); s1+=__expf(v.w-m1);} }
  s0=wsumf(s0); s1=wsumf(s1);
  const float lse0=m0+__logf(s0), lse1=m1+__logf(s1);

  // ---- per-row cost -> monotone keys (16 per lane) ----
  uint key[16];
  const float p0=p01.x, pp1=p01.y;
#pragma unroll
  for(int t=0;t<16;++t){
    int i=t*64+lane; uint kk=0xFFFFFFFFu;         // phantom sorts above everything
    if(i<NROWS){
      float4 v=sRow[i];
      float ls0=v.z-lse0, ls1=v.w-lse1;
      float e0=__expf(ls0), e1=__expf(ls1);
      float focal=(1.f-e0)*(1.f-e0)*ls0*p0 + (1.f-e1)*(1.f-e1)*ls1*pp1;
      float prod=v.y*(v.x*(1.f/72.f))*inv;
      float cost=3.f*prod*prod+focal;
      uint x=__float_as_uint(cost);
      kk=(x&0x80000000u)?~x:(x|0x80000000u);
    }
    key[t]=kk;
  }

  // ---- k-th smallest: 32x 1-bit ballot binary search ----
  uint pref=0u, r=(uint)k;
  for(int s=31;s>=0;--s){
    const uint pp=pref>>s;
    uint cnt=0u;
#pragma unroll
    for(int t=0;t<16;++t) cnt += (uint)__popcll(__ballot((key[t]>>s)==pp));
    if(r>cnt){ r-=cnt; pref|=(1u<<s); }
  }
  const uint T2=pref; uint need=r;                // all <T2 plus first `need` ==T2

  // ---- selection: ballot-prefix compaction ----
  const ull lmask=(1ull<<lane)-1ull;
  int base=0;
#pragma unroll
  for(int t=0;t<16;++t){
    bool lt = key[t]<T2;
    bool eq = key[t]==T2;
    ull meq=__ballot(eq);
    bool eqs = eq && ((uint)__popcll(meq&lmask)<need);
    uint teq=(uint)__popcll(meq);
    need -= (teq<need?teq:need);
    bool ssel = lt||eqs;
    ull ms=__ballot(ssel);
    if(ssel) selIdx[base+(int)__popcll(ms&lmask)] = t*64+lane;
    base += (int)__popcll(ms);
  }

  // ---- Phase C ----
  {
    bool act = lane<k;
    int idx = selIdx[act?lane:0];
    const float2* R2=(const float2*)(F+(size_t)idx*78);
    float2 g01=R2[0], g23=R2[1], g45=R2[2];
    float S = sRow[idx].x;
    float mk = act?1.f:0.f;
    float n2=wsumf(g23.x*g23.x*mk), n3=wsumf(g23.y*g23.y*mk);
    float n4=wsumf(g45.x*g45.x*mk), n5=wsumf(g45.y*g45.y*mk);
    float l2=p23.x, l3=p23.y, l4=p45.x, l5=p45.y;
    float de2=fmaxf(sqrtf(n2+l2*l2),1e-12f);
    float de3=fmaxf(sqrtf(n3+l3*l3),1e-12f);
    float de4=fmaxf(sqrtf(n4+l4*l4),1e-12f);
    float de5=fmaxf(sqrtf(n5+l5*l5),1e-12f);
    float d2=g23.x/de2-l2/de2, d3=g23.y/de3-l3/de3, d4=g45.x/de4-l4/de4, d5=g45.y/de5-l5/de5;
    auto h=[](float d){ float ad=fabsf(d); return ad<1.f ? 0.5f*d*d : ad-0.5f; };
    float sl1 = 0.25f*(h(d2)+h(d3)+h(d4)+h(d5));
    float mm=fmaxf(g01.x,g01.y);
    float lsee=mm+__logf(__expf(g01.x-mm)+__expf(g01.y-mm));
    float logpt=((pp1>p0)?g01.y:g01.x)-lsee;      // tgt=argmax(prior[:2]), first-max -> 0
    float pt=__expf(logpt);
    float fl=-(1.f-pt)*(1.f-pt)*logpt;
    float ll=1.f-(TWO_R_N-S)/(TWO_R_N+S+1e-9f);
    float ssl=wsumf(sl1*mk), sll=wsumf(ll*mk), sfl=wsumf(fl*mk);
    if(lane==0){
      float invk=1.f/(float)k;
      float* o = ws + (size_t)(b*16+l)*3;
      o[0]=ssl*invk; o[1]=sll*invk; o[2]=sfl*invk;
    }
  }
}

__global__ __launch_bounds__(256) void clr_finalize(const float* __restrict__ ws,
                                                    float* __restrict__ out)
{
  float a=0.f, bsum=0.f, c=0.f;
  for(int i=threadIdx.x;i<1024;i+=256){
    a    += ws[i*3+0];
    bsum += ws[i*3+1];
    c    += ws[i*3+2];
  }
  a=wsumf(a); bsum=wsumf(bsum); c=wsumf(c);
  __shared__ float r[12];
  int wave=threadIdx.x>>6, lane=threadIdx.x&63;
  if(lane==0){ r[wave*3]=a; r[wave*3+1]=bsum; r[wave*3+2]=c; }
  __syncthreads();
  if(threadIdx.x==0){
    float sa=0,sb=0,sc=0;
    for(int w=0;w<4;w++){sa+=r[w*3];sb+=r[w*3+1];sc+=r[w*3+2];}
    float sl1l=sa*(1.f/1024.f), ll=sb*(1.f/1024.f), fl=sc*(1.f/1024.f);
    // LW_XYTL=0.5, LW_LIOU=2.0, LW_CLS=2.0
    float loss = (sl1l>0.f ? 0.5f*sl1l : 0.f)
               + (ll  >0.f ? 2.0f*ll   : 0.f)
               + (fl  >0.f ? 2.0f*fl   : 0.f);
    out[0]=loss;
  }
}

extern "C" void kernel_launch(void* const* d_in, const int* in_sizes, int n_in,
                              void* d_out, int out_size, void* d_ws, size_t ws_size,
                              hipStream_t stream)
{
  const float* feat = (const float*)d_in[0];   // (64,1000,78) f32
  const float* lab  = (const float*)d_in[1];   // (64,16,78)  f32
  float* ws  = (float*)d_ws;                   // 1024*3 floats, fully overwritten
  float* out = (float*)d_out;
  hipLaunchKernelGGL(clr_task, dim3(1024), dim3(256), 0, stream, feat, lab, ws);
  hipLaunchKernelGGL(clr_finalize, dim3(1), dim3(256), 0, stream, ws, out);
}

// Round 9
// 101.209 us; speedup vs baseline: 1.6312x; 1.6312x over previous
//
#include <hip/hip_runtime.h>
#include <math.h>

#define NROWS 1000
#define TWO_R_N 2160.0f   // 2*RADIUS*NUM_POINTS
typedef unsigned int uint;
typedef unsigned long long ull;

__device__ __forceinline__ float wsumf(float v){
#pragma unroll
  for(int o=32;o;o>>=1) v += __shfl_xor(v,o,64);
  return v;
}
__device__ __forceinline__ float wmaxf(float v){
#pragma unroll
  for(int o=32;o;o>>=1) v = fmaxf(v,__shfl_xor(v,o,64));
  return v;
}

// async global->LDS DMA, 16B per lane; lds dst = wave-uniform base + lane*16
__device__ __forceinline__ void dma16(const float4* g, float4* l){
  __builtin_amdgcn_global_load_lds((const __attribute__((address_space(1))) void*)g,
                                   (__attribute__((address_space(3))) void*)l,
                                   16, 0, 0);
}

// 1024 blocks = 64 batches x 16 priors; 4 blocks/CU share batch b = x&63 via L2.
// Pass 1: global_load_lds DMA staging (no VGPR round-trip -> no spill)
//         -> quad-per-row b32-grid reads (2-way banks = free) -> SoA row stats.
__global__ __launch_bounds__(256,4) void clr_task(const float* __restrict__ feat,
                                                  const float* __restrict__ lab,
                                                  float* __restrict__ ws)
{
  const int b = blockIdx.x & 63;
  const int l = blockIdx.x >> 6;
  const float* __restrict__ F = feat + (size_t)b*NROWS*78;
  const float* __restrict__ P = lab + ((size_t)b*16 + l)*78;

  __shared__ __align__(16) float4 sBuf4[1280];    // 64-row chunk (1248) + 32 pad slots
  __shared__ float sS[NROWS];                     // SoA row stats: stride-1 sweeps
  __shared__ float sRT[NROWS];
  __shared__ float sC0[NROWS];
  __shared__ float sC1[NROWS];
  __shared__ float red[16];
  __shared__ int selIdx[64];

  const int tid=threadIdx.x, wave=tid>>6, lane=tid&63;
  const int rloc = tid>>2, q = tid&3;             // quad-per-row within chunk

  // prior: 18 interleaved point-columns for this q (uniform per quad-slot, L1-cached)
  float pv[18];
#pragma unroll
  for(int s=0;s<18;++s) pv[s] = P[6+q+4*s];
  const float2* Pf2 = (const float2*)P;
  const float2 p01=Pf2[0], p23=Pf2[1], p45=Pf2[2];

  float accR=0.f, accT=0.f, accD=0.f, accL=0.f;

  for(int c=0;c<16;++c){
    __syncthreads();                              // chunk c-1 reads complete
    // DMA chunk c: 5 wave-segments of 64 float4; global idx clamped in-range
    {
      const float4* src4=(const float4*)(F + (size_t)c*4992);
      const int limit = (c==15)?779:1247;         // chunk 15 = 40 rows = 780 float4
#pragma unroll
      for(int it=0;it<5;++it){
        int base = it*256 + wave*64;
        int idx  = base + lane;
        dma16(src4 + (idx>limit?limit:idx), sBuf4 + base);
      }
    }
    __syncthreads();                              // vmcnt drained -> chunk resident
    // compute chunk c: thread q reads cols {6+q+4s}; banks 2-way = free
    const int rows = (c<15)?64:40;
    if(rloc<rows){
      const float* rp = (const float*)sBuf4 + rloc*78;
      float part=0.f;
#pragma unroll
      for(int s=0;s<9;++s){
        part += fabsf(rp[6+q+4*s]      - pv[s]);
        part += fabsf(rp[6+q+4*(s+9)]  - pv[s+9]);
      }
      float s1 = part + __shfl_xor(part,1,64);
      float S  = s1   + __shfl_xor(s1,  2,64);
      if(q==0){
        int r = c*64 + rloc;
        const float2* rp2=(const float2*)rp;
        float2 c01=rp2[0], c23=rp2[1], c45=rp2[2];
        float dr3=c23.y-p23.y, dr4=c45.x-p45.x;
        float r2=dr3*dr3+dr4*dr4;
        float tt=c45.y-p45.y;
        sS[r]=S; sRT[r]=sqrtf(r2)*tt; sC0[r]=c01.x; sC1[r]=c01.y;
        accR+=r2; accT+=tt*tt;
        float dd=S*(1.f/72.f); accD+=dd*dd;
        accL += 1.f-(TWO_R_N-S)/(TWO_R_N+S+1e-9f);
      }
    }
  }

  {
    float vR=wsumf(accR), vT=wsumf(accT), vD=wsumf(accD), vL=wsumf(accL);
    if(lane==0){ red[wave*4]=vR; red[wave*4+1]=vT; red[wave*4+2]=vD; red[wave*4+3]=vL; }
  }
  __syncthreads();
  if (wave != 0) return;                          // waves 1-3 free their SIMD slots

  // ---- wave-0 tail: normalizers ----
  float R=0.f,T=0.f,D=0.f,L=0.f;
#pragma unroll
  for(int w=0;w<4;w++){ R+=red[w*4]; T+=red[w*4+1]; D+=red[w*4+2]; L+=red[w*4+3]; }
  float Nr=fmaxf(sqrtf(R),1e-12f), Nt=fmaxf(sqrtf(T),1e-12f), Nd=fmaxf(sqrtf(D),1e-12f);
  const float inv = 1.f/(Nr*Nt*Nd);
  int k=(int)L; if(k<1)k=1; if(k>64)k=64;         // trunc == astype(int32)

  // ---- column log-softmax over 1000 rows (stride-1 SoA sweeps, conflict-free) ----
  float m0=-INFINITY, m1=-INFINITY;
#pragma unroll
  for(int t=0;t<16;++t){ int i=t*64+lane; if(i<NROWS){ m0=fmaxf(m0,sC0[i]); m1=fmaxf(m1,sC1[i]);} }
  m0=wmaxf(m0); m1=wmaxf(m1);
  float s0=0.f, s1=0.f;
#pragma unroll
  for(int t=0;t<16;++t){ int i=t*64+lane; if(i<NROWS){ s0+=__expf(sC0[i]-m0); s1+=__expf(sC1[i]-m1);} }
  s0=wsumf(s0); s1=wsumf(s1);
  const float lse0=m0+__logf(s0), lse1=m1+__logf(s1);

  // ---- per-row cost -> monotone keys (16 per lane) ----
  uint key[16];
  const float p0=p01.x, pp1=p01.y;
#pragma unroll
  for(int t=0;t<16;++t){
    int i=t*64+lane; uint kk=0xFFFFFFFFu;         // phantom sorts above everything
    if(i<NROWS){
      float ls0=sC0[i]-lse0, ls1=sC1[i]-lse1;
      float e0=__expf(ls0), e1=__expf(ls1);
      float focal=(1.f-e0)*(1.f-e0)*ls0*p0 + (1.f-e1)*(1.f-e1)*ls1*pp1;
      float prod=sRT[i]*(sS[i]*(1.f/72.f))*inv;
      float cost=3.f*prod*prod+focal;
      uint x=__float_as_uint(cost);
      kk=(x&0x80000000u)?~x:(x|0x80000000u);
    }
    key[t]=kk;
  }

  // ---- k-th smallest: 32x 1-bit ballot binary search ----
  uint pref=0u, r=(uint)k;
  for(int s=31;s>=0;--s){
    const uint pp=pref>>s;
    uint cnt=0u;
#pragma unroll
    for(int t=0;t<16;++t) cnt += (uint)__popcll(__ballot((key[t]>>s)==pp));
    if(r>cnt){ r-=cnt; pref|=(1u<<s); }
  }
  const uint T2=pref; uint need=r;                // all <T2 plus first `need` ==T2

  // ---- selection: ballot-prefix compaction ----
  const ull lmask=(1ull<<lane)-1ull;
  int base=0;
#pragma unroll
  for(int t=0;t<16;++t){
    bool lt = key[t]<T2;
    bool eq = key[t]==T2;
    ull meq=__ballot(eq);
    bool eqs = eq && ((uint)__popcll(meq&lmask)<need);
    uint teq=(uint)__popcll(meq);
    need -= (teq<need?teq:need);
    bool ssel = lt||eqs;
    ull ms=__ballot(ssel);
    if(ssel) selIdx[base+(int)__popcll(ms&lmask)] = t*64+lane;
    base += (int)__popcll(ms);
  }

  // ---- Phase C ----
  {
    bool act = lane<k;
    int idx = selIdx[act?lane:0];
    const float2* R2=(const float2*)(F+(size_t)idx*78);
    float2 g01=R2[0], g23=R2[1], g45=R2[2];
    float S = sS[idx];
    float mk = act?1.f:0.f;
    float n2=wsumf(g23.x*g23.x*mk), n3=wsumf(g23.y*g23.y*mk);
    float n4=wsumf(g45.x*g45.x*mk), n5=wsumf(g45.y*g45.y*mk);
    float l2=p23.x, l3=p23.y, l4=p45.x, l5=p45.y;
    float de2=fmaxf(sqrtf(n2+l2*l2),1e-12f);
    float de3=fmaxf(sqrtf(n3+l3*l3),1e-12f);
    float de4=fmaxf(sqrtf(n4+l4*l4),1e-12f);
    float de5=fmaxf(sqrtf(n5+l5*l5),1e-12f);
    float d2=g23.x/de2-l2/de2, d3=g23.y/de3-l3/de3, d4=g45.x/de4-l4/de4, d5=g45.y/de5-l5/de5;
    auto h=[](float d){ float ad=fabsf(d); return ad<1.f ? 0.5f*d*d : ad-0.5f; };
    float sl1 = 0.25f*(h(d2)+h(d3)+h(d4)+h(d5));
    float mm=fmaxf(g01.x,g01.y);
    float lsee=mm+__logf(__expf(g01.x-mm)+__expf(g01.y-mm));
    float logpt=((pp1>p0)?g01.y:g01.x)-lsee;      // tgt=argmax(prior[:2]), first-max -> 0
    float pt=__expf(logpt);
    float fl=-(1.f-pt)*(1.f-pt)*logpt;
    float ll=1.f-(TWO_R_N-S)/(TWO_R_N+S+1e-9f);
    float ssl=wsumf(sl1*mk), sll=wsumf(ll*mk), sfl=wsumf(fl*mk);
    if(lane==0){
      float invk=1.f/(float)k;
      float* o = ws + (size_t)(b*16+l)*3;
      o[0]=ssl*invk; o[1]=sll*invk; o[2]=sfl*invk;
    }
  }
}

__global__ __launch_bounds__(256) void clr_finalize(const float* __restrict__ ws,
                                                    float* __restrict__ out)
{
  float a=0.f, bsum=0.f, c=0.f;
  for(int i=threadIdx.x;i<1024;i+=256){
    a    += ws[i*3+0];
    bsum += ws[i*3+1];
    c    += ws[i*3+2];
  }
  a=wsumf(a); bsum=wsumf(bsum); c=wsumf(c);
  __shared__ float r[12];
  int wave=threadIdx.x>>6, lane=threadIdx.x&63;
  if(lane==0){ r[wave*3]=a; r[wave*3+1]=bsum; r[wave*3+2]=c; }
  __syncthreads();
  if(threadIdx.x==0){
    float sa=0,sb=0,sc=0;
    for(int w=0;w<4;w++){sa+=r[w*3];sb+=r[w*3+1];sc+=r[w*3+2];}
    float sl1l=sa*(1.f/1024.f), ll=sb*(1.f/1024.f), fl=sc*(1.f/1024.f);
    // LW_XYTL=0.5, LW_LIOU=2.0, LW_CLS=2.0
    float loss = (sl1l>0.f ? 0.5f*sl1l : 0.f)
               + (ll  >0.f ? 2.0f*ll   : 0.f)
               + (fl  >0.f ? 2.0f*fl   : 0.f);
    out[0]=loss;
  }
}

extern "C" void kernel_launch(void* const* d_in, const int* in_sizes, int n_in,
                              void* d_out, int out_size, void* d_ws, size_t ws_size,
                              hipStream_t stream)
{
  const float* feat = (const float*)d_in[0];   // (64,1000,78) f32
  const float* lab  = (const float*)d_in[1];   // (64,16,78)  f32
  float* ws  = (float*)d_ws;                   // 1024*3 floats, fully overwritten
  float* out = (float*)d_out;
  hipLaunchKernelGGL(clr_task, dim3(1024), dim3(256), 0, stream, feat, lab, ws);
  hipLaunchKernelGGL(clr_finalize, dim3(1), dim3(256), 0, stream, ws, out);
}

// Round 10
// 100.379 us; speedup vs baseline: 1.6446x; 1.0083x over previous
//
#include <hip/hip_runtime.h>
#include <math.h>

#define NROWS 1000
#define TWO_R_N 2160.0f   // 2*RADIUS*NUM_POINTS
typedef unsigned int uint;
typedef unsigned long long ull;

__device__ __forceinline__ float wsumf(float v){
#pragma unroll
  for(int o=32;o;o>>=1) v += __shfl_xor(v,o,64);
  return v;
}
__device__ __forceinline__ float wmaxf(float v){
#pragma unroll
  for(int o=32;o;o>>=1) v = fmaxf(v,__shfl_xor(v,o,64));
  return v;
}

// async global->LDS DMA, 16B/lane; lds dst = wave-uniform base + lane*16
__device__ __forceinline__ void dma16(const float4* g, float4* l){
  __builtin_amdgcn_global_load_lds((const __attribute__((address_space(1))) void*)g,
                                   (__attribute__((address_space(3))) void*)l,
                                   16, 0, 0);
}

// 256 blocks = 64 batches x 4 prior-groups; 1024 threads = 16 waves.
// wave = 4*rowgroup + prior_in_group. F staged ONCE per block (double-buffered
// DMA, one barrier per chunk); tail per prior on waves 0..3.
__global__ __launch_bounds__(1024,1) void clr_task(const float* __restrict__ feat,
                                                   const float* __restrict__ lab,
                                                   float* __restrict__ ws)
{
  const int b  = blockIdx.x & 63;   // same-batch blocks share an XCD (blockIdx%8 = b%8)
  const int pg = blockIdx.x >> 6;
  const float* __restrict__ F = feat + (size_t)b*NROWS*78;

  __shared__ __align__(16) float4 sBuf4[2][1280]; // 64-row chunk x2 (40960 B)
  __shared__ float sS[4][NROWS];                  // per-prior S      (16000 B)
  __shared__ float sRT[4][NROWS];                 // per-prior r*t    (16000 B)
  __shared__ float sC0[NROWS], sC1[NROWS];        // shared c0,c1     ( 8000 B)
  __shared__ float red[64];
  __shared__ int selIdx[4][64];

  const int tid=threadIdx.x, wave=tid>>6, lane=tid&63;
  const int pw = wave & 3;                        // prior within group
  const int rg = wave >> 2;                       // row-group within chunk
  const int rloc16 = lane>>2, q = lane&3;

  const float* __restrict__ P = lab + ((size_t)b*16 + pg*4 + pw)*78;
  float pv[18];
#pragma unroll
  for(int s=0;s<18;++s) pv[s] = P[6+q+4*s];
  const float2* Pf2 = (const float2*)P;
  const float2 p01=Pf2[0], p23=Pf2[1], p45=Pf2[2];

  float accR=0.f, accT=0.f, accD=0.f, accL=0.f;

  // prologue: DMA chunk 0 -> buf 0
  {
    const float4* src4=(const float4*)F;
#pragma unroll
    for(int it=0;it<2;++it){
      int base = it*1024 + wave*64;
      if(base<=1247){
        int idx = base + lane;
        dma16(src4 + (idx>1247?1247:idx), &sBuf4[0][base]);
      }
    }
  }

  for(int c=0;c<16;++c){
    __syncthreads();   // drains my DMAs (chunk c resident) + compute c-1 done
    if(c<15){          // DMA chunk c+1 into the other buffer; flies during compute c
      const int limit = (c+1==15)?779:1247;
      const float4* src4=(const float4*)(F + (size_t)(c+1)*4992);
#pragma unroll
      for(int it=0;it<2;++it){
        int base = it*1024 + wave*64;
        if(base<=limit){
          int idx = base + lane;
          dma16(src4 + (idx>limit?limit:idx), &sBuf4[(c+1)&1][base]);
        }
      }
    }
    // compute chunk c: wave handles rows rg*16..rg*16+15 for prior pw
    const int rows = (c<15)?64:40;
    const int rr = rg*16 + rloc16;
    if(rr<rows){
      const float* rp = (const float*)(&sBuf4[c&1][0]) + rr*78;
      float part=0.f;
#pragma unroll
      for(int s=0;s<9;++s){
        part += fabsf(rp[6+q+4*s]     - pv[s]);
        part += fabsf(rp[6+q+4*(s+9)] - pv[s+9]);
      }
      float s1 = part + __shfl_xor(part,1,64);
      float S  = s1   + __shfl_xor(s1,  2,64);
      if(q==0){
        int r = c*64 + rr;
        const float2* rp2=(const float2*)rp;
        float2 c01=rp2[0], c23=rp2[1], c45=rp2[2];
        float dr3=c23.y-p23.y, dr4=c45.x-p45.x;
        float r2=dr3*dr3+dr4*dr4;
        float tt=c45.y-p45.y;
        sS[pw][r]=S; sRT[pw][r]=sqrtf(r2)*tt;
        if(pw==0){ sC0[r]=c01.x; sC1[r]=c01.y; }
        accR+=r2; accT+=tt*tt;
        float dd=S*(1.f/72.f); accD+=dd*dd;
        accL += 1.f-(TWO_R_N-S)/(TWO_R_N+S+1e-9f);
      }
    }
  }

  {
    float vR=wsumf(accR), vT=wsumf(accT), vD=wsumf(accD), vL=wsumf(accL);
    if(lane==0){ red[wave*4]=vR; red[wave*4+1]=vT; red[wave*4+2]=vD; red[wave*4+3]=vL; }
  }
  __syncthreads();
  if (wave >= 4) return;                          // tail: wave w = prior w (rg==0 -> pw==wave)
  const int w = wave;

  // ---- per-prior normalizers (combine the 4 row-group waves of prior w) ----
  float R=0.f,T=0.f,D=0.f,L=0.f;
#pragma unroll
  for(int g=0;g<4;++g){
    int src=(4*g+w)*4;
    R+=red[src]; T+=red[src+1]; D+=red[src+2]; L+=red[src+3];
  }
  float Nr=fmaxf(sqrtf(R),1e-12f), Nt=fmaxf(sqrtf(T),1e-12f), Nd=fmaxf(sqrtf(D),1e-12f);
  const float inv = 1.f/(Nr*Nt*Nd);
  int k=(int)L; if(k<1)k=1; if(k>64)k=64;         // trunc == astype(int32)

  // ---- column log-softmax over 1000 rows (stride-1 sweeps, conflict-free) ----
  float m0=-INFINITY, m1=-INFINITY;
#pragma unroll
  for(int t=0;t<16;++t){ int i=t*64+lane; if(i<NROWS){ m0=fmaxf(m0,sC0[i]); m1=fmaxf(m1,sC1[i]);} }
  m0=wmaxf(m0); m1=wmaxf(m1);
  float s0=0.f, s1=0.f;
#pragma unroll
  for(int t=0;t<16;++t){ int i=t*64+lane; if(i<NROWS){ s0+=__expf(sC0[i]-m0); s1+=__expf(sC1[i]-m1);} }
  s0=wsumf(s0); s1=wsumf(s1);
  const float lse0=m0+__logf(s0), lse1=m1+__logf(s1);

  // ---- per-row cost -> monotone keys (16 per lane) ----
  uint key[16];
  const float p0=p01.x, pp1=p01.y;
#pragma unroll
  for(int t=0;t<16;++t){
    int i=t*64+lane; uint kk=0xFFFFFFFFu;         // phantom sorts above everything
    if(i<NROWS){
      float ls0=sC0[i]-lse0, ls1=sC1[i]-lse1;
      float e0=__expf(ls0), e1=__expf(ls1);
      float focal=(1.f-e0)*(1.f-e0)*ls0*p0 + (1.f-e1)*(1.f-e1)*ls1*pp1;
      float prod=sRT[w][i]*(sS[w][i]*(1.f/72.f))*inv;
      float cost=3.f*prod*prod+focal;
      uint x=__float_as_uint(cost);
      kk=(x&0x80000000u)?~x:(x|0x80000000u);
    }
    key[t]=kk;
  }

  // ---- k-th smallest: 32x 1-bit ballot binary search ----
  uint pref=0u, r=(uint)k;
  for(int s=31;s>=0;--s){
    const uint pp=pref>>s;
    uint cnt=0u;
#pragma unroll
    for(int t=0;t<16;++t) cnt += (uint)__popcll(__ballot((key[t]>>s)==pp));
    if(r>cnt){ r-=cnt; pref|=(1u<<s); }
  }
  const uint T2=pref; uint need=r;                // all <T2 plus first `need` ==T2

  // ---- selection: ballot-prefix compaction ----
  const ull lmask=(1ull<<lane)-1ull;
  int base=0;
#pragma unroll
  for(int t=0;t<16;++t){
    bool lt = key[t]<T2;
    bool eq = key[t]==T2;
    ull meq=__ballot(eq);
    bool eqs = eq && ((uint)__popcll(meq&lmask)<need);
    uint teq=(uint)__popcll(meq);
    need -= (teq<need?teq:need);
    bool ssel = lt||eqs;
    ull ms=__ballot(ssel);
    if(ssel) selIdx[w][base+(int)__popcll(ms&lmask)] = t*64+lane;
    base += (int)__popcll(ms);
  }

  // ---- Phase C ----
  {
    bool act = lane<k;
    int idx = selIdx[w][act?lane:0];
    const float2* R2=(const float2*)(F+(size_t)idx*78);
    float2 g01=R2[0], g23=R2[1], g45=R2[2];
    float S = sS[w][idx];
    float mk = act?1.f:0.f;
    float n2=wsumf(g23.x*g23.x*mk), n3=wsumf(g23.y*g23.y*mk);
    float n4=wsumf(g45.x*g45.x*mk), n5=wsumf(g45.y*g45.y*mk);
    float l2=p23.x, l3=p23.y, l4=p45.x, l5=p45.y;
    float de2=fmaxf(sqrtf(n2+l2*l2),1e-12f);
    float de3=fmaxf(sqrtf(n3+l3*l3),1e-12f);
    float de4=fmaxf(sqrtf(n4+l4*l4),1e-12f);
    float de5=fmaxf(sqrtf(n5+l5*l5),1e-12f);
    float d2=g23.x/de2-l2/de2, d3=g23.y/de3-l3/de3, d4=g45.x/de4-l4/de4, d5=g45.y/de5-l5/de5;
    auto h=[](float d){ float ad=fabsf(d); return ad<1.f ? 0.5f*d*d : ad-0.5f; };
    float sl1 = 0.25f*(h(d2)+h(d3)+h(d4)+h(d5));
    float mm=fmaxf(g01.x,g01.y);
    float lsee=mm+__logf(__expf(g01.x-mm)+__expf(g01.y-mm));
    float logpt=((pp1>p0)?g01.y:g01.x)-lsee;      // tgt=argmax(prior[:2]), first-max -> 0
    float pt=__expf(logpt);
    float fl=-(1.f-pt)*(1.f-pt)*logpt;
    float ll=1.f-(TWO_R_N-S)/(TWO_R_N+S+1e-9f);
    float ssl=wsumf(sl1*mk), sll=wsumf(ll*mk), sfl=wsumf(fl*mk);
    if(lane==0){
      float invk=1.f/(float)k;
      float* o = ws + (size_t)(b*16 + pg*4 + w)*3;
      o[0]=ssl*invk; o[1]=sll*invk; o[2]=sfl*invk;
    }
  }
}

__global__ __launch_bounds__(256) void clr_finalize(const float* __restrict__ ws,
                                                    float* __restrict__ out)
{
  float a=0.f, bsum=0.f, c=0.f;
  for(int i=threadIdx.x;i<1024;i+=256){
    a    += ws[i*3+0];
    bsum += ws[i*3+1];
    c    += ws[i*3+2];
  }
  a=wsumf(a); bsum=wsumf(bsum); c=wsumf(c);
  __shared__ float r[12];
  int wave=threadIdx.x>>6, lane=threadIdx.x&63;
  if(lane==0){ r[wave*3]=a; r[wave*3+1]=bsum; r[wave*3+2]=c; }
  __syncthreads();
  if(threadIdx.x==0){
    float sa=0,sb=0,sc=0;
    for(int w2=0;w2<4;w2++){sa+=r[w2*3];sb+=r[w2*3+1];sc+=r[w2*3+2];}
    float sl1l=sa*(1.f/1024.f), ll=sb*(1.f/1024.f), fl=sc*(1.f/1024.f);
    // LW_XYTL=0.5, LW_LIOU=2.0, LW_CLS=2.0
    float loss = (sl1l>0.f ? 0.5f*sl1l : 0.f)
               + (ll  >0.f ? 2.0f*ll   : 0.f)
               + (fl  >0.f ? 2.0f*fl   : 0.f);
    out[0]=loss;
  }
}

extern "C" void kernel_launch(void* const* d_in, const int* in_sizes, int n_in,
                              void* d_out, int out_size, void* d_ws, size_t ws_size,
                              hipStream_t stream)
{
  const float* feat = (const float*)d_in[0];   // (64,1000,78) f32
  const float* lab  = (const float*)d_in[1];   // (64,16,78)  f32
  float* ws  = (float*)d_ws;                   // 1024*3 floats, fully overwritten
  float* out = (float*)d_out;
  hipLaunchKernelGGL(clr_task, dim3(256), dim3(1024), 0, stream, feat, lab, ws);
  hipLaunchKernelGGL(clr_finalize, dim3(1), dim3(256), 0, stream, ws, out);
}